// Round 1
// baseline (4999.195 us; speedup 1.0000x reference)
//
#include <hip/hip_runtime.h>
#include <cstdint>
#include <cstddef>

// ---------------- problem constants ----------------
#define V_SZ 50257
#define H_SZ 512
#define S_SZ 128
#define NBEAM 5
#define TMAXX 32
#define TOK_SOS 1
#define TOK_EOS 2
#define NEGINF (-1e9f)

// ---------------- launch shape ----------------
#define GW 128            // workgroups (<=256 CUs -> co-resident)
#define NT 512            // threads per WG (8 waves)
#define GENC 16           // encoder sub-group WGs
#define COLS_PER_WG 393   // ceil(V/GW)

// ---------------- barrier area (ints at start of ws; memset to 0 each launch) ----------------
#define BI_ROOT  0
#define BI_GEN   32
#define BI_LEAF0 64       // leaf i at BI_LEAF0 + i*32  (8 leaves of 16 WGs)
#define BI_ECNT  320
#define BI_EGEN  352
#define BI_EDONE 384

// ---------------- float workspace offsets (from (float*)ws + 1024) ----------------
#define OF_GI    0            // 128*1536 encoder gi = emb@Wih^T + bih
#define OF_ENC   196608       // 128*512 encoder hidden states
#define OF_EW    262144       // 128*512 EW = enc_out @ Wc_bottom
#define OF_H2    327680       // 5*512 decoder GRU output
#define OF_HID   330240       // 5*512 persistent hidden
#define OF_AL    332800       // 5*128 attention logits
#define OF_P     333440       // 5*128 exp(al - max)
#define OF_SS    334080       // 8: softmax sums per beam
#define OF_OTOP  334088       // 2560: h2 @ Wc_top
#define OF_O     336648       // 2560: final o (tanh)
#define OF_PV    339208       // 128*5*5 per-WG per-beam top5 vals
#define OF_PM    342408       // 128*5 per-WG per-beam max
#define OF_PS    343048       // 128*5 per-WG per-beam sumexp
#define OF_SCORE 343688       // 5 beam scores
#define OI_BASE  343696       // int region begins here (float-index)
//   ints (relative): 0: ptop_idx[3200]; 3200: tok[5]; 3205: fin[5]; 3210: len[5]; 3216: seqs[2][5][32]

__device__ __forceinline__ float wredsum(float a){
#pragma unroll
  for (int m = 32; m; m >>= 1) a += __shfl_xor(a, m, 64);
  return a;
}

__device__ __forceinline__ void spin_until_ne(int* p, int g){
  while (__hip_atomic_load(p, __ATOMIC_RELAXED, __HIP_MEMORY_SCOPE_AGENT) == g)
    __builtin_amdgcn_s_sleep(2);
}

// device-wide barrier, two-level tree; last-arriving WG runs tail() before release
template <typename F>
__device__ __forceinline__ void gbar(int* bi, int wid, F&& tail){
  __shared__ int s_last;
  int mygen = 0;
  __syncthreads();
  if (threadIdx.x == 0){
    __threadfence();
    mygen = __hip_atomic_load(bi + BI_GEN, __ATOMIC_RELAXED, __HIP_MEMORY_SCOPE_AGENT);
    int last = 0;
    int leaf = wid >> 4;
    int lo = __hip_atomic_fetch_add(bi + BI_LEAF0 + leaf*32, 1, __ATOMIC_ACQ_REL, __HIP_MEMORY_SCOPE_AGENT);
    if (lo == 15){
      __hip_atomic_store(bi + BI_LEAF0 + leaf*32, 0, __ATOMIC_RELAXED, __HIP_MEMORY_SCOPE_AGENT);
      int ro = __hip_atomic_fetch_add(bi + BI_ROOT, 1, __ATOMIC_ACQ_REL, __HIP_MEMORY_SCOPE_AGENT);
      if (ro == (GW/16) - 1){
        __hip_atomic_store(bi + BI_ROOT, 0, __ATOMIC_RELAXED, __HIP_MEMORY_SCOPE_AGENT);
        __threadfence();   // acquire all other WGs' data before tail reads it
        last = 1;
      }
    }
    s_last = last;
  }
  __syncthreads();
  if (s_last){
    tail();
    __syncthreads();
    if (threadIdx.x == 0){
      __threadfence();     // publish tail's writes
      __hip_atomic_fetch_add(bi + BI_GEN, 1, __ATOMIC_RELEASE, __HIP_MEMORY_SCOPE_AGENT);
    }
  } else {
    if (threadIdx.x == 0){
      spin_until_ne(bi + BI_GEN, mygen);
      __threadfence();     // acquire released data
    }
  }
  __syncthreads();
}

// 16-WG encoder barrier (flat)
__device__ __forceinline__ void ebar(int* bi){
  __syncthreads();
  if (threadIdx.x == 0){
    __threadfence();
    int g = __hip_atomic_load(bi + BI_EGEN, __ATOMIC_RELAXED, __HIP_MEMORY_SCOPE_AGENT);
    int lo = __hip_atomic_fetch_add(bi + BI_ECNT, 1, __ATOMIC_ACQ_REL, __HIP_MEMORY_SCOPE_AGENT);
    if (lo == GENC - 1){
      __hip_atomic_store(bi + BI_ECNT, 0, __ATOMIC_RELAXED, __HIP_MEMORY_SCOPE_AGENT);
      __hip_atomic_fetch_add(bi + BI_EGEN, 1, __ATOMIC_RELEASE, __HIP_MEMORY_SCOPE_AGENT);
    } else {
      spin_until_ne(bi + BI_EGEN, g);
    }
    __threadfence();
  }
  __syncthreads();
}

__global__ __launch_bounds__(NT, 1)
void beam_kernel(const int* __restrict__ toks, const float* __restrict__ emb,
                 const float* __restrict__ eWih, const float* __restrict__ eWhh,
                 const float* __restrict__ ebih, const float* __restrict__ ebhh,
                 const float* __restrict__ dWih, const float* __restrict__ dWhh,
                 const float* __restrict__ dbih, const float* __restrict__ dbhh,
                 const float* __restrict__ Wc,  const float* __restrict__ Wv,
                 float* __restrict__ out, float* __restrict__ ws)
{
  const int wid = blockIdx.x, tid = threadIdx.x;
  const int lane = tid & 63, wvi = tid >> 6;
  int* bi = (int*)ws;
  float* fb = ws + 1024;
  float* gi   = fb + OF_GI;
  float* enc  = fb + OF_ENC;
  float* EW   = fb + OF_EW;
  float* h2   = fb + OF_H2;
  float* hid  = fb + OF_HID;
  float* al   = fb + OF_AL;
  float* pp   = fb + OF_P;
  float* Ssm  = fb + OF_SS;
  float* otop = fb + OF_OTOP;
  float* oo   = fb + OF_O;
  float* pv   = fb + OF_PV;
  float* pm   = fb + OF_PM;
  float* ps   = fb + OF_PS;
  float* sc   = fb + OF_SCORE;
  int* ib   = (int*)(fb + OI_BASE);
  int* pidx = ib + 0;
  int* tokA = ib + 3200;
  int* finA = ib + 3205;
  int* lenA = ib + 3210;
  int* seqA = ib + 3216;   // [2][5][32]

  __shared__ float smF[1024];
  __shared__ int   smI[256];

  // ================= Phase 0: gi_enc GEMM + state init =================
  {
    int Wg = wid*8 + wvi;                 // global wave id 0..1023
    for (int it = 0; it < 192; ++it){
      int idx = Wg*192 + it;              // covers 128*1536 exactly
      int s = idx / 1536, j = idx - s*1536;
      const float* er = emb + (size_t)toks[s]*H_SZ;
      const float* wr = eWih + (size_t)j*H_SZ;
      float a = 0.f;
#pragma unroll
      for (int u = 0; u < 8; ++u) a += er[u*64+lane]*wr[u*64+lane];
      a = wredsum(a);
      if (lane == 0) gi[idx] = a + ebih[j];
    }
    if (wid == 0){
      if (tid < NBEAM){
        sc[tid] = (tid==0) ? 0.f : NEGINF;
        tokA[tid] = TOK_SOS; finA[tid] = 0; lenA[tid] = 1;
      }
      for (int q = tid; q < 2*NBEAM*TMAXX; q += NT) seqA[q] = 0;
    }
  }
  gbar(bi, wid, [&](){});

  // ================= Phase 1: sequential encoder (16 WGs) =================
  if (wid < GENC){
    int i0 = wid*32;
    for (int s = 0; s < S_SZ; ++s){
      const float* hp = enc + (size_t)(s-1)*H_SZ;
      float hreg[8];
#pragma unroll
      for (int u = 0; u < 8; ++u) hreg[u] = (s==0) ? 0.f : hp[u*64+lane];
      for (int dd = 0; dd < 12; ++dd){
        int d = wvi*12 + dd;              // 0..95: g = d/32, il = d%32
        int g = d >> 5, il = d & 31;
        const float* wr = eWhh + (size_t)(g*512 + i0 + il)*H_SZ;
        float a = 0.f;
#pragma unroll
        for (int u = 0; u < 8; ++u) a += wr[u*64+lane]*hreg[u];
        a = wredsum(a);
        if (lane == 0) smF[d] = a;
      }
      __syncthreads();
      if (tid < 32){
        int i = i0 + tid;
        float gr = smF[tid], gz = smF[32+tid], gn = smF[64+tid];
        float gir = gi[s*1536 + i], giz = gi[s*1536 + 512 + i], gin = gi[s*1536 + 1024 + i];
        float hprev = (s==0) ? 0.f : enc[(s-1)*H_SZ + i];
        float r = 1.f/(1.f + expf(-(gir + gr + ebhh[i])));
        float z = 1.f/(1.f + expf(-(giz + gz + ebhh[512+i])));
        float n = tanhf(gin + r*(gn + ebhh[1024+i]));
        enc[s*H_SZ + i] = (1.f - z)*n + z*hprev;
      }
      ebar(bi);
    }
    if (wid == 0 && tid == 0){
      __threadfence();
      __hip_atomic_store(bi + BI_EDONE, 1, __ATOMIC_RELEASE, __HIP_MEMORY_SCOPE_AGENT);
    }
  }
  if (tid == 0){
    while (__hip_atomic_load(bi + BI_EDONE, __ATOMIC_RELAXED, __HIP_MEMORY_SCOPE_AGENT) == 0)
      __builtin_amdgcn_s_sleep(4);
    __threadfence();
  }
  __syncthreads();

  // ================= Phase 2: EW = enc_out @ Wc_bottom (once) =================
  {
    int jc = wid & 15, sb = wid >> 4;
    int jl = tid & 31, sl = (tid >> 5) & 15;
    int s = sb*16 + sl, j = jc*32 + jl;
    const float* er = enc + (size_t)s*H_SZ;
    const float* wc = Wc + (size_t)512*H_SZ;
    float a = 0.f;
    for (int k = 0; k < 512; ++k) a += er[k]*wc[(size_t)k*H_SZ + j];
    EW[s*H_SZ + j] = a;
  }
  gbar(bi, wid, [&](){});

  // ================= decode loop =================
  for (int t = 0; t < TMAXX; ++t){

    // ---- Stage A: decoder GRU -> h2 (WG owns i-chunk of 4 x all 5 beams) ----
    {
      int i0 = wid*4;
      int mat = wvi >> 2;                       // waves 0-3: Wih (x); 4-7: Whh (h)
      float srg[5][8];
#pragma unroll
      for (int b = 0; b < NBEAM; ++b){
        const float* sp;
        if (mat == 0) sp = emb + (size_t)tokA[b]*H_SZ;
        else          sp = (t == 0) ? (enc + 127*H_SZ) : (hid + b*H_SZ);
#pragma unroll
        for (int u = 0; u < 8; ++u) srg[b][u] = sp[u*64+lane];
      }
      for (int rr = 0; rr < 3; ++rr){
        int R = wvi*3 + rr;                     // 0..23
        int rem = R - mat*12;                   // = R%12 (wave-aligned)
        int g = rem >> 2, il = rem & 3;
        const float* wr = ((mat==0) ? dWih : dWhh) + (size_t)(g*512 + i0 + il)*H_SZ;
        float wreg[8];
#pragma unroll
        for (int u = 0; u < 8; ++u) wreg[u] = wr[u*64+lane];
#pragma unroll
        for (int b = 0; b < NBEAM; ++b){
          float a = 0.f;
#pragma unroll
          for (int u = 0; u < 8; ++u) a += wreg[u]*srg[b][u];
          a = wredsum(a);
          if (lane == 0) smF[R*5 + b] = a;
        }
      }
      __syncthreads();
      if (tid < 20){
        int b = tid >> 2, il = tid & 3;
        int i = i0 + il;
        float ir  = smF[(0*12 + 0*4 + il)*5 + b] + dbih[i];
        float iz  = smF[(0*12 + 1*4 + il)*5 + b] + dbih[512+i];
        float inn = smF[(0*12 + 2*4 + il)*5 + b] + dbih[1024+i];
        float hr  = smF[(1*12 + 0*4 + il)*5 + b] + dbhh[i];
        float hz  = smF[(1*12 + 1*4 + il)*5 + b] + dbhh[512+i];
        float hn  = smF[(1*12 + 2*4 + il)*5 + b] + dbhh[1024+i];
        float r = 1.f/(1.f + expf(-(ir + hr)));
        float z = 1.f/(1.f + expf(-(iz + hz)));
        float n = tanhf(inn + r*hn);
        float hp = (t == 0) ? enc[127*H_SZ + i] : hid[b*H_SZ + i];
        h2[b*H_SZ + i] = (1.f - z)*n + z*hp;
      }
    }
    gbar(bi, wid, [&](){});

    // ---- Stage B1: attention logits (s = wid) + o_top = h2 @ Wc_top ----
    {
      if (wvi < NBEAM){
        const float* er = enc + (size_t)wid*H_SZ;
        const float* hb = h2 + wvi*H_SZ;
        float a = 0.f;
#pragma unroll
        for (int u = 0; u < 8; ++u) a += er[u*64+lane]*hb[u*64+lane];
        a = wredsum(a);
        if (lane == 0) al[wvi*S_SZ + wid] = a;
      }
      if (tid < 320){
        int q = tid % 20, ksl = tid / 20;
        int f = wid*20 + q;
        int b = f >> 9, j = f & 511;
        float a = 0.f;
#pragma unroll 8
        for (int u = 0; u < 32; ++u){
          int k = ksl*32 + u;
          a += h2[b*H_SZ + k]*Wc[(size_t)k*H_SZ + j];
        }
        smF[q*16 + ksl] = a;
      }
      __syncthreads();
      if (tid < 20){
        float a = 0.f;
#pragma unroll
        for (int u = 0; u < 16; ++u) a += smF[tid*16 + u];
        otop[wid*20 + tid] = a;
      }
    }
    gbar(bi, wid, [&](){
      // tail: softmax (exp(x-max) and sum; normalization folded into B2)
      if (wvi < NBEAM){
        float a1 = al[wvi*S_SZ + lane], a2 = al[wvi*S_SZ + 64 + lane];
        float m = fmaxf(a1, a2);
#pragma unroll
        for (int mm = 32; mm; mm >>= 1) m = fmaxf(m, __shfl_xor(m, mm, 64));
        float e1 = expf(a1 - m), e2 = expf(a2 - m);
        pp[wvi*S_SZ + lane] = e1; pp[wvi*S_SZ + 64 + lane] = e2;
        float ssv = wredsum(e1 + e2);
        if (lane == 0) Ssm[wvi] = ssv;
      }
    });

    // ---- Stage B2: o = tanh(o_top + (sum_s p_s * EW[s]) / S) ----
    {
      if (tid < 320){
        int q = tid % 20, ssl = tid / 20;
        int f = wid*20 + q;
        int b = f >> 9, j = f & 511;
        float a = 0.f;
#pragma unroll
        for (int u = 0; u < 8; ++u){
          int s = ssl*8 + u;
          a += pp[b*S_SZ + s]*EW[(size_t)s*H_SZ + j];
        }
        smF[q*16 + ssl] = a;
      }
      __syncthreads();
      if (tid < 20){
        float a = 0.f;
#pragma unroll
        for (int u = 0; u < 16; ++u) a += smF[tid*16 + u];
        int f = wid*20 + tid;
        int b = f >> 9;
        oo[f] = tanhf(otop[f] + a/Ssm[b]);
      }
    }
    gbar(bi, wid, [&](){});

    // ---- Stage C: logits over vocab chunk + per-beam (top5, max, sumexp) partials ----
    {
      int vbase = wid*COLS_PER_WG;
      int v = vbase + tid;
      bool act = (tid < COLS_PER_WG) && (v < V_SZ);
      int vc = act ? v : vbase;
      const float* wp = Wv + vc;
      const float* og = oo;
      float a0=0.f,a1=0.f,a2=0.f,a3=0.f,a4=0.f;
      for (int hb = 0; hb < H_SZ; hb += 16){
        float wr[16];
#pragma unroll
        for (int u = 0; u < 16; ++u) wr[u] = wp[(size_t)(hb+u)*V_SZ];
#pragma unroll
        for (int u = 0; u < 16; ++u){
          float w = wr[u];
          a0 += w*og[hb+u];
          a1 += w*og[512+hb+u];
          a2 += w*og[1024+hb+u];
          a3 += w*og[1536+hb+u];
          a4 += w*og[2048+hb+u];
        }
      }
      if (!act){ a0=a1=a2=a3=a4=-3e38f; }
      int myv = act ? v : 0x7FFFFFFF;
      float accs[5] = {a0,a1,a2,a3,a4};
#pragma unroll
      for (int b = 0; b < NBEAM; ++b){
        float x = accs[b];
        float m = x;
#pragma unroll
        for (int mm = 32; mm; mm >>= 1) m = fmaxf(m, __shfl_xor(m, mm, 64));
        float e = expf(x - m);
        float ssum = wredsum(e);
        // wave top5 (5 rounds of argmax; ties -> lower v)
        float bv = x; int bc = myv;
        float w5[5]; int i5[5];
#pragma unroll
        for (int r = 0; r < 5; ++r){
          float cv2 = bv; int ci2 = bc;
#pragma unroll
          for (int mm = 32; mm; mm >>= 1){
            float ov = __shfl_xor(cv2, mm, 64); int oi = __shfl_xor(ci2, mm, 64);
            bool take = (ov > cv2) || (ov == cv2 && oi < ci2);
            cv2 = take ? ov : cv2; ci2 = take ? oi : ci2;
          }
          w5[r] = cv2; i5[r] = ci2;
          if (bc == ci2) bv = -3e38f;
        }
        if (lane == 0){
#pragma unroll
          for (int r = 0; r < 5; ++r){ smF[(wvi*5+b)*5+r] = w5[r]; smI[(wvi*5+b)*5+r] = i5[r]; }
          smF[300 + wvi*5 + b] = m;
          smF[360 + wvi*5 + b] = ssum;
        }
      }
      __syncthreads();
      if (tid < NBEAM){   // merge (m,s) across 8 waves
        float M = -3.4e38f, Sv = 0.f;
#pragma unroll
        for (int w8 = 0; w8 < 8; ++w8){
          float m2 = smF[300 + w8*5 + tid], s2 = smF[360 + w8*5 + tid];
          if (m2 > M){ Sv = Sv*expf(M - m2) + s2; M = m2; }
          else       { Sv = Sv + s2*expf(m2 - M); }
        }
        pm[wid*5 + tid] = M; ps[wid*5 + tid] = Sv;
      }
      if (wvi < NBEAM){   // wave b merges the 8 wave-top5s of beam b
        int b = wvi;
        float cval; int cidx;
        if (lane < 40){ cval = smF[((lane/5)*5 + b)*5 + (lane%5)]; cidx = smI[((lane/5)*5 + b)*5 + (lane%5)]; }
        else { cval = -3e38f; cidx = 0x7FFFFFFF; }
        float bv = cval; int bc = cidx;
#pragma unroll
        for (int r = 0; r < 5; ++r){
          float cv2 = bv; int ci2 = bc;
#pragma unroll
          for (int mm = 32; mm; mm >>= 1){
            float ov = __shfl_xor(cv2, mm, 64); int oi = __shfl_xor(ci2, mm, 64);
            bool take = (ov > cv2) || (ov == cv2 && oi < ci2);
            cv2 = take ? ov : cv2; ci2 = take ? oi : ci2;
          }
          if (lane == 0){ pv[(wid*5+b)*5+r] = cv2; pidx[(wid*5+b)*5+r] = ci2; }
          if (bc == ci2) bv = -3e38f;
        }
      }
    }
    gbar(bi, wid, [&](){
      // ======== Stage D (barrier tail, one WG): merge partials, top-k, state update ========
      int b5 = wvi;
      if (b5 < NBEAM){
        // global lse parts: M and log(S)
        float m1 = pm[lane*5 + b5], s1 = ps[lane*5 + b5];
        float m2 = pm[(64+lane)*5 + b5], s2 = ps[(64+lane)*5 + b5];
        float M, Sv;
        if (m1 >= m2){ M = m1; Sv = s1 + s2*expf(m2 - m1); }
        else         { M = m2; Sv = s2 + s1*expf(m1 - m2); }
#pragma unroll
        for (int mm = 32; mm; mm >>= 1){
          float om = __shfl_xor(M, mm, 64), os = __shfl_xor(Sv, mm, 64);
          if (om > M){ Sv = Sv*expf(M - om) + os; M = om; }
          else       { Sv = Sv + os*expf(om - M); }
        }
        if (lane == 0){ smF[8 + b5] = M; smF[80 + b5] = logf(Sv); }
        // global per-beam top5: each lane merges 2 WGs' sorted-5 lists, then k-way pop-merge
        float lv[5]; int li[5];
#pragma unroll
        for (int r = 0; r < 5; ++r){ lv[r] = pv[(lane*5 + b5)*5 + r]; li[r] = pidx[(lane*5 + b5)*5 + r]; }
        for (int r = 0; r < 5; ++r){
          float nv = pv[((64+lane)*5 + b5)*5 + r]; int ni = pidx[((64+lane)*5 + b5)*5 + r];
          bool ins = (nv > lv[4]) || (nv == lv[4] && ni < li[4]);
          if (!ins) break;
          lv[4] = nv; li[4] = ni;
#pragma unroll
          for (int p = 4; p > 0; --p){
            bool sw = (lv[p] > lv[p-1]) || (lv[p] == lv[p-1] && li[p] < li[p-1]);
            if (sw){ float tv = lv[p]; lv[p] = lv[p-1]; lv[p-1] = tv;
                     int ti = li[p]; li[p] = li[p-1]; li[p-1] = ti; }
          }
        }
        float cv = lv[0]; int ci = li[0];
#pragma unroll
        for (int r = 0; r < 5; ++r){
          float xv = cv; int xi = ci;
#pragma unroll
          for (int mm = 32; mm; mm >>= 1){
            float ov = __shfl_xor(xv, mm, 64); int oi = __shfl_xor(xi, mm, 64);
            bool take = (ov > xv) || (ov == xv && oi < xi);
            xv = take ? ov : xv; xi = take ? oi : xi;
          }
          if (lane == 0){ smF[16 + b5*5 + r] = xv; smI[16 + b5*5 + r] = xi; }
          if (ci == xi){
            lv[0]=lv[1]; li[0]=li[1]; lv[1]=lv[2]; li[1]=li[2];
            lv[2]=lv[3]; li[2]=li[3]; lv[3]=lv[4]; li[3]=li[4];
            lv[4] = -3e38f; li[4] = 0x7FFFFFFF;
            cv = lv[0]; ci = li[0];
          }
        }
      }
      __syncthreads();
      if (wvi == 0){
        // build 25 candidates; finished beams contribute a single EOS candidate
        float cval = -3e38f; int cflat = 0x7FFFFFFF;
        int b = lane/5, k = lane - b*5;
        if (lane < 25){
          if (finA[b]){
            if (k == 0){ cval = sc[b] + 0.0f; cflat = b*V_SZ + TOK_EOS; }
          } else {
            // exact reference order: ((x - m) - logS) + score
            cval = ((smF[16 + b*5 + k] - smF[8 + b]) - smF[80 + b]) + sc[b];
            cflat = b*V_SZ + smI[16 + b*5 + k];
          }
        }
        float bv = cval; int bc = cflat;
#pragma unroll
        for (int r = 0; r < 5; ++r){
          float xv = bv; int xi = bc;
#pragma unroll
          for (int mm = 32; mm; mm >>= 1){
            float ov = __shfl_xor(xv, mm, 64); int oi = __shfl_xor(xi, mm, 64);
            bool take = (ov > xv) || (ov == xv && oi < xi);
            xv = take ? ov : xv; xi = take ? oi : xi;
          }
          if (lane == 0){ smF[48 + r] = xv; smI[48 + r] = xi; }
          if (bc == xi) bv = -3e38f;
        }
        if (lane < NBEAM){
          int r = lane;
          float nscore = smF[48 + r]; int nfl = smI[48 + r];
          int par = nfl / V_SZ; int tok = nfl - par*V_SZ;
          int ofin = finA[par]; int olen = lenA[par];   // wave-lockstep: all reads before writes
          int nf = (ofin || tok == TOK_EOS) ? 1 : 0;
          int nl = olen + (ofin ? 0 : 1);
          sc[r] = nscore; tokA[r] = tok; finA[r] = nf; lenA[r] = nl;
          smI[56 + r] = par; smI[64 + r] = tok; smI[72 + r] = ofin; smI[80 + r] = nl;
          smF[56 + r] = nscore;
        }
      }
      __syncthreads();
      int cur = t & 1, nxt = 1 - cur;
      if (tid < 160){
        int r = tid >> 5, u = tid & 31;
        int par = smI[56 + r];
        int val = seqA[cur*160 + par*32 + u];
        if (u == t) val = smI[72 + r] ? 0 : smI[64 + r];
        seqA[nxt*160 + r*32 + u] = val;
      }
#pragma unroll
      for (int r = 0; r < NBEAM; ++r){
        int par = smI[56 + r];
        hid[r*H_SZ + tid] = h2[par*H_SZ + tid];
      }
      if (t == TMAXX - 1){
        __syncthreads();
        if (tid == 0){
          float nn[5];
#pragma unroll
          for (int r = 0; r < 5; ++r) nn[r] = smF[56 + r] / (float)smI[80 + r];
          int used = 0;
#pragma unroll
          for (int r = 0; r < 5; ++r){
            int best = -1;
            for (int q2 = 0; q2 < 5; ++q2){
              if (used & (1 << q2)) continue;
              if (best < 0 || nn[q2] > nn[best]) best = q2;   // strict >: stable (lower index on tie)
            }
            used |= (1 << best);
            smI[88 + r] = best; smF[64 + r] = nn[best];
          }
        }
        __syncthreads();
        if (tid < 160){
          int r = tid >> 5, u = tid & 31;
          int src = smI[88 + r];
          out[tid] = (float)seqA[nxt*160 + src*32 + u];
        }
        if (tid >= 160 && tid < 165) out[tid] = smF[64 + (tid - 160)];
      }
    });
  }
}

extern "C" void kernel_launch(void* const* d_in, const int* in_sizes, int n_in,
                              void* d_out, int out_size, void* d_ws, size_t ws_size,
                              hipStream_t stream)
{
  (void)in_sizes; (void)n_in; (void)out_size; (void)ws_size;
  // barrier/flag region must be zero at kernel start (ws is poisoned before every launch)
  hipMemsetAsync(d_ws, 0, 4096, stream);
  beam_kernel<<<dim3(GW), dim3(NT), 0, stream>>>(
      (const int*)d_in[0],  (const float*)d_in[1],
      (const float*)d_in[2], (const float*)d_in[3],
      (const float*)d_in[4], (const float*)d_in[5],
      (const float*)d_in[6], (const float*)d_in[7],
      (const float*)d_in[8], (const float*)d_in[9],
      (const float*)d_in[10], (const float*)d_in[11],
      (float*)d_out, (float*)d_ws);
}

// Round 2
// 3695.798 us; speedup vs baseline: 1.3527x; 1.3527x over previous
//
#include <hip/hip_runtime.h>
#include <cstdint>
#include <cstddef>

// ---------------- problem constants ----------------
#define V_SZ 50257
#define H_SZ 512
#define S_SZ 128
#define NBEAM 5
#define TMAXX 32
#define TOK_SOS 1
#define TOK_EOS 2
#define NEGINF (-1e9f)

// ---------------- launch shape ----------------
#define GW 128            // decode workgroups
#define NT 512
#define GENC 16           // encoder WGs (Whh register-resident: 96 rows * 512 f32 each)
#define COLS_PER_WG 393   // ceil(V/GW)

// ---------------- barrier ints (start of ws; first 8 KiB memset to 0) ----------------
#define BI_LEAF(l)  ((l)*32)        // 8 leaf counters (16 WGs each)
#define BI_ROOT     256
#define BI_REL(l)   (512 + (l)*32)  // 8 per-leaf release generations
#define BI_ECNT     1024
#define BI_EREL     1056

// ---------------- float region: fb = (float*)ws + 2048 ----------------
#define OF_GI    0            // 128*1536
#define OF_ENC   196608       // 128*512
#define OF_EW    262144       // 128*512  enc_out @ Wc_bottom
#define OF_H2    327680       // [2][5][512] ping-pong decoder hidden
#define OF_AL    332800       // [5][128] attention logits
#define OF_OTOP  333440       // [5][512] h2 @ Wc_top (flat b*512+j)
#define OF_PV    336000       // [128][5][5]
#define OF_PM    339200       // [128][5]
#define OF_PS    339840       // [128][5]
#define OF_SC    340480       // [8]
#define OI_BASE  340488
// int region (relative): pidx 0, tokA 3200, finA 3208, lenA 3216, parA 3224, seqA 3232 (+320)

template <typename T>
__device__ __forceinline__ T aload(const T* p){
  return __hip_atomic_load((T*)p, __ATOMIC_RELAXED, __HIP_MEMORY_SCOPE_AGENT);
}
template <typename T>
__device__ __forceinline__ void astore(T* p, T v){
  __hip_atomic_store(p, v, __ATOMIC_RELAXED, __HIP_MEMORY_SCOPE_AGENT);
}

__device__ __forceinline__ float wredsum(float a){
#pragma unroll
  for (int m = 32; m; m >>= 1) a += __shfl_xor(a, m, 64);
  return a;
}

// fence-free device barrier over GW WGs; last-arriving WG runs tail() before release.
// Mutable cross-WG data must travel through agent-scope relaxed atomics (sc1 -> L3);
// __syncthreads drains each wave's vmcnt so all sc1 stores are at L3 before arrive.
template <typename F>
__device__ __forceinline__ void dbar(int* bi, int wid, F&& tail){
  __shared__ int s_last;
  int mygen = 0;
  __syncthreads();
  if (threadIdx.x == 0){
    int leaf = wid >> 4;
    mygen = aload(bi + BI_REL(leaf));
    __builtin_amdgcn_s_waitcnt(0);
    int lo = __hip_atomic_fetch_add(bi + BI_LEAF(leaf), 1, __ATOMIC_RELAXED, __HIP_MEMORY_SCOPE_AGENT);
    int last = 0;
    if (lo == 15){
      astore(bi + BI_LEAF(leaf), 0);
      __builtin_amdgcn_s_waitcnt(0);     // leaf reset at L3 before root arrive
      int ro = __hip_atomic_fetch_add(bi + BI_ROOT, 1, __ATOMIC_RELAXED, __HIP_MEMORY_SCOPE_AGENT);
      if (ro == (GW/16) - 1){
        astore(bi + BI_ROOT, 0);
        last = 1;
      }
    }
    if (!last){
      while (aload(bi + BI_REL(leaf)) == mygen) __builtin_amdgcn_s_sleep(4);
    }
    s_last = last;
  }
  __syncthreads();
  if (s_last){
    tail();
    __syncthreads();
    if (threadIdx.x == 0){
      __builtin_amdgcn_s_waitcnt(0);     // tail's sc1 stores + root reset at L3
#pragma unroll
      for (int l = 0; l < GW/16; ++l) astore(bi + BI_REL(l), mygen + 1);
    }
  }
  __syncthreads();
}

// ================= K1: gi = src_emb @ eWih^T + bih, plus beam-state init =================
__global__ __launch_bounds__(256)
void k_gi(const int* __restrict__ toks, const float* __restrict__ emb,
          const float* __restrict__ eWih, const float* __restrict__ ebih,
          float* __restrict__ ws)
{
  float* fb = ws + 2048;
  float* gi = fb + OF_GI;
  const int tid = threadIdx.x, wid = blockIdx.x, lane = tid & 63, wvi = tid >> 6;
  int Wg = wid*4 + wvi;                 // 0..1023
  for (int it = 0; it < 192; ++it){
    int idx = Wg*192 + it;              // covers 128*1536
    int s = idx / 1536, j = idx - s*1536;
    const float* er = emb + (size_t)toks[s]*H_SZ;
    const float* wr = eWih + (size_t)j*H_SZ;
    float a = 0.f;
#pragma unroll
    for (int u = 0; u < 8; ++u) a += er[u*64+lane]*wr[u*64+lane];
    a = wredsum(a);
    if (lane == 0) gi[idx] = a + ebih[j];
  }
  if (wid == 0){
    float* sc = fb + OF_SC;
    int* ib = (int*)(fb + OI_BASE);
    if (tid < NBEAM){
      sc[tid] = (tid==0) ? 0.f : NEGINF;
      ib[3200+tid] = TOK_SOS; ib[3208+tid] = 0; ib[3216+tid] = 1; ib[3224+tid] = 0;
    }
    for (int q = tid; q < 2*NBEAM*TMAXX; q += 256) ib[3232+q] = 0;
  }
}

// ================= K2: sequential encoder, 16 WGs, Whh in registers =================
__global__ __launch_bounds__(NT, 1)
void k_enc(const float* __restrict__ eWhh, const float* __restrict__ ebhh,
           float* __restrict__ ws)
{
  int* bi = (int*)ws;
  float* fb = ws + 2048;
  float* gi = fb + OF_GI;
  float* enc = fb + OF_ENC;
  const int tid = threadIdx.x, wid = blockIdx.x, lane = tid & 63, wvi = tid >> 6;
  const int i0 = wid*32;
  __shared__ float smF[96];

  // preload this wave's 12 Whh rows into registers (96 VGPRs/thread)
  float wreg[12][8];
#pragma unroll
  for (int dd = 0; dd < 12; ++dd){
    int d = wvi*12 + dd, g = d >> 5, il = d & 31;
    const float* wr = eWhh + (size_t)(g*512 + i0 + il)*H_SZ;
#pragma unroll
    for (int u = 0; u < 8; ++u) wreg[dd][u] = wr[u*64+lane];
  }

  for (int s = 0; s < S_SZ; ++s){
    float hreg[8];
    if (s == 0){
#pragma unroll
      for (int u = 0; u < 8; ++u) hreg[u] = 0.f;
    } else {
      const float* hp = enc + (size_t)(s-1)*H_SZ;
#pragma unroll
      for (int u = 0; u < 8; ++u) hreg[u] = aload(hp + u*64 + lane);
    }
#pragma unroll
    for (int dd = 0; dd < 12; ++dd){
      float a = 0.f;
#pragma unroll
      for (int u = 0; u < 8; ++u) a += wreg[dd][u]*hreg[u];
      a = wredsum(a);
      if (lane == 0) smF[wvi*12 + dd] = a;
    }
    __syncthreads();
    if (tid < 32){
      int i = i0 + tid;
      float gr = smF[tid], gz = smF[32+tid], gn = smF[64+tid];
      float gir = gi[s*1536 + i], giz = gi[s*1536 + 512 + i], gin = gi[s*1536 + 1024 + i];
      float hprev = (s==0) ? 0.f : aload(enc + (s-1)*H_SZ + i);
      float r = 1.f/(1.f + expf(-(gir + gr + ebhh[i])));
      float z = 1.f/(1.f + expf(-(giz + gz + ebhh[512+i])));
      float n = tanhf(gin + r*(gn + ebhh[1024+i]));
      astore(enc + s*H_SZ + i, (1.f - z)*n + z*hprev);
    }
    // fence-free 16-WG barrier
    __syncthreads();
    if (tid == 0){
      int g = aload(bi + BI_EREL);
      __builtin_amdgcn_s_waitcnt(0);
      int lo = __hip_atomic_fetch_add(bi + BI_ECNT, 1, __ATOMIC_RELAXED, __HIP_MEMORY_SCOPE_AGENT);
      if (lo == GENC - 1){
        astore(bi + BI_ECNT, 0);
        __builtin_amdgcn_s_waitcnt(0);
        astore(bi + BI_EREL, g + 1);
      } else {
        while (aload(bi + BI_EREL) == g) __builtin_amdgcn_s_sleep(2);
      }
    }
    __syncthreads();
  }
}

// ================= K3: EW = enc_out @ Wc_bottom =================
__global__ __launch_bounds__(NT)
void k_ew(const float* __restrict__ Wc, float* __restrict__ ws)
{
  float* fb = ws + 2048;
  float* enc = fb + OF_ENC;
  float* EW  = fb + OF_EW;
  const int tid = threadIdx.x, wid = blockIdx.x;
  int jc = wid & 15, sb = wid >> 4;
  int jl = tid & 31, sl = (tid >> 5) & 15;
  int s = sb*16 + sl, j = jc*32 + jl;
  const float* er = enc + (size_t)s*H_SZ;       // plain: kernel boundary made it visible
  const float* wc = Wc + (size_t)512*H_SZ;
  float a = 0.f;
  for (int k = 0; k < 512; ++k) a += er[k]*wc[(size_t)k*H_SZ + j];
  EW[s*H_SZ + j] = a;
}

// ================= K4: persistent decode, 3 fence-free barriers/step =================
__global__ __launch_bounds__(NT, 1)
void k_dec(const float* __restrict__ emb,
           const float* __restrict__ dWih, const float* __restrict__ dWhh,
           const float* __restrict__ dbih, const float* __restrict__ dbhh,
           const float* __restrict__ Wc,  const float* __restrict__ Wv,
           float* __restrict__ out, float* __restrict__ ws)
{
  const int wid = blockIdx.x, tid = threadIdx.x;
  const int lane = tid & 63, wvi = tid >> 6;
  int* bi = (int*)ws;
  float* fb = ws + 2048;
  float* enc  = fb + OF_ENC;
  float* EW   = fb + OF_EW;
  float* h2   = fb + OF_H2;
  float* al   = fb + OF_AL;
  float* otop = fb + OF_OTOP;
  float* pv   = fb + OF_PV;
  float* pm   = fb + OF_PM;
  float* ps   = fb + OF_PS;
  float* sc   = fb + OF_SC;
  int* ib   = (int*)(fb + OI_BASE);
  int* pidx = ib;
  int* tokA = ib + 3200;
  int* finA = ib + 3208;
  int* lenA = ib + 3216;
  int* parA = ib + 3224;
  int* seqA = ib + 3232;   // [2][5][32]

  __shared__ float smF[1024];
  __shared__ int   smI[256];
  __shared__ float s_buf[2560];   // stage A: h_prev rows; stage B: h2new; stage C: oo
  __shared__ float s_pp[648];     // softmax exp + sums

  for (int t = 0; t < TMAXX; ++t){
    float* h2new = h2 + (t & 1)*2560;
    float* h2old = h2 + ((t & 1) ^ 1)*2560;

    // ---- Stage A: decoder GRU ----
    if (tid < NBEAM){ smI[tid] = aload(tokA + tid); smI[8 + tid] = t ? aload(parA + tid) : 0; }
    __syncthreads();
    if (t == 0){
      for (int q = tid; q < 2560; q += NT) s_buf[q] = enc[127*H_SZ + (q & 511)];
    } else {
      for (int q = tid; q < 2560; q += NT){
        int b = q >> 9;
        s_buf[q] = aload(h2old + smI[8 + b]*H_SZ + (q & 511));
      }
    }
    __syncthreads();
    {
      int i0 = wid*4;
      int mat = wvi >> 2;                       // waves 0-3: Wih(x); 4-7: Whh(h)
      float srg[5][8];
      if (mat == 0){
#pragma unroll
        for (int b = 0; b < NBEAM; ++b){
          const float* sp = emb + (size_t)smI[b]*H_SZ;
#pragma unroll
          for (int u = 0; u < 8; ++u) srg[b][u] = sp[u*64+lane];
        }
      } else {
#pragma unroll
        for (int b = 0; b < NBEAM; ++b)
#pragma unroll
          for (int u = 0; u < 8; ++u) srg[b][u] = s_buf[b*512 + u*64 + lane];
      }
      for (int rr = 0; rr < 3; ++rr){
        int R = wvi*3 + rr;                     // 0..23
        int rem = R - mat*12;
        int g = rem >> 2, il = rem & 3;
        const float* wr = ((mat==0) ? dWih : dWhh) + (size_t)(g*512 + i0 + il)*H_SZ;
        float wreg[8];
#pragma unroll
        for (int u = 0; u < 8; ++u) wreg[u] = wr[u*64+lane];
#pragma unroll
        for (int b = 0; b < NBEAM; ++b){
          float a = 0.f;
#pragma unroll
          for (int u = 0; u < 8; ++u) a += wreg[u]*srg[b][u];
          a = wredsum(a);
          if (lane == 0) smF[R*5 + b] = a;
        }
      }
      __syncthreads();
      if (tid < 20){
        int b = tid >> 2, il = tid & 3;
        int i = i0 + il;
        float ir  = smF[(0*12 + 0*4 + il)*5 + b] + dbih[i];
        float iz  = smF[(0*12 + 1*4 + il)*5 + b] + dbih[512+i];
        float inn = smF[(0*12 + 2*4 + il)*5 + b] + dbih[1024+i];
        float hr  = smF[(1*12 + 0*4 + il)*5 + b] + dbhh[i];
        float hz  = smF[(1*12 + 1*4 + il)*5 + b] + dbhh[512+i];
        float hn  = smF[(1*12 + 2*4 + il)*5 + b] + dbhh[1024+i];
        float r = 1.f/(1.f + expf(-(ir + hr)));
        float z = 1.f/(1.f + expf(-(iz + hz)));
        float n = tanhf(inn + r*hn);
        float hp = s_buf[b*512 + i];
        astore(h2new + b*H_SZ + i, (1.f - z)*n + z*hp);
      }
    }
    dbar(bi, wid, [&](){});

    // ---- Stage B: attention logits (s = wid) + otop = h2 @ Wc_top ----
    for (int q = tid; q < 2560; q += NT) s_buf[q] = aload(h2new + q);
    __syncthreads();
    if (wvi < NBEAM){
      const float* er = enc + (size_t)wid*H_SZ;
      float a = 0.f;
#pragma unroll
      for (int u = 0; u < 8; ++u) a += er[u*64+lane]*s_buf[wvi*512 + u*64 + lane];
      a = wredsum(a);
      if (lane == 0) astore(al + wvi*S_SZ + wid, a);
    }
    if (tid < 320){
      int q = tid % 20, ksl = tid / 20;
      int f = wid*20 + q;
      int b = f >> 9, j = f & 511;
      float a = 0.f;
#pragma unroll 8
      for (int u = 0; u < 32; ++u){
        int k = ksl*32 + u;
        a += s_buf[b*512 + k]*Wc[(size_t)k*H_SZ + j];
      }
      smF[q*16 + ksl] = a;
    }
    __syncthreads();
    if (tid < 20){
      float a = 0.f;
#pragma unroll
      for (int u = 0; u < 16; ++u) a += smF[tid*16 + u];
      astore(otop + wid*20 + tid, a);
    }
    dbar(bi, wid, [&](){});

    // ---- Stage C: local softmax + o, vocab GEMM, per-WG partials ----
    if (wvi < NBEAM){
      float a1 = aload(al + wvi*S_SZ + lane), a2 = aload(al + wvi*S_SZ + 64 + lane);
      float m = fmaxf(a1, a2);
#pragma unroll
      for (int mm = 32; mm; mm >>= 1) m = fmaxf(m, __shfl_xor(m, mm, 64));
      float e1 = expf(a1 - m), e2 = expf(a2 - m);
      s_pp[wvi*128 + lane] = e1; s_pp[wvi*128 + 64 + lane] = e2;
      float ssv = wredsum(e1 + e2);
      if (lane == 0) s_pp[640 + wvi] = ssv;
    }
    __syncthreads();
    {
      float acc[5] = {0.f,0.f,0.f,0.f,0.f};
      for (int s2 = 0; s2 < 128; ++s2){
        float e = EW[(size_t)s2*H_SZ + tid];
#pragma unroll
        for (int b = 0; b < NBEAM; ++b) acc[b] += e*s_pp[b*128 + s2];
      }
#pragma unroll
      for (int b = 0; b < NBEAM; ++b)
        s_buf[b*512 + tid] = tanhf(aload(otop + b*512 + tid) + acc[b]/s_pp[640 + b]);
    }
    __syncthreads();
    {
      int vbase = wid*COLS_PER_WG;
      int v = vbase + tid;
      bool act = (tid < COLS_PER_WG) && (v < V_SZ);
      int vc = act ? v : vbase;
      const float* wp = Wv + vc;
      float a0=0.f,a1=0.f,a2=0.f,a3=0.f,a4=0.f;
      for (int hb = 0; hb < H_SZ; hb += 16){
        float wr[16];
#pragma unroll
        for (int u = 0; u < 16; ++u) wr[u] = wp[(size_t)(hb+u)*V_SZ];
#pragma unroll
        for (int u = 0; u < 16; ++u){
          float w = wr[u];
          a0 += w*s_buf[hb+u];
          a1 += w*s_buf[512+hb+u];
          a2 += w*s_buf[1024+hb+u];
          a3 += w*s_buf[1536+hb+u];
          a4 += w*s_buf[2048+hb+u];
        }
      }
      if (!act){ a0=a1=a2=a3=a4=-3e38f; }
      int myv = act ? v : 0x7FFFFFFF;
      float accs[5] = {a0,a1,a2,a3,a4};
#pragma unroll
      for (int b = 0; b < NBEAM; ++b){
        float x = accs[b];
        float m = x;
#pragma unroll
        for (int mm = 32; mm; mm >>= 1) m = fmaxf(m, __shfl_xor(m, mm, 64));
        float e = expf(x - m);
        float ssum = wredsum(e);
        float bv = x; int bc = myv;
        float w5[5]; int i5[5];
#pragma unroll
        for (int r = 0; r < 5; ++r){
          float cv2 = bv; int ci2 = bc;
#pragma unroll
          for (int mm = 32; mm; mm >>= 1){
            float ov = __shfl_xor(cv2, mm, 64); int oi = __shfl_xor(ci2, mm, 64);
            bool take = (ov > cv2) || (ov == cv2 && oi < ci2);
            cv2 = take ? ov : cv2; ci2 = take ? oi : ci2;
          }
          w5[r] = cv2; i5[r] = ci2;
          if (bc == ci2) bv = -3e38f;
        }
        if (lane == 0){
#pragma unroll
          for (int r = 0; r < 5; ++r){ smF[(wvi*5+b)*5+r] = w5[r]; smI[(wvi*5+b)*5+r] = i5[r]; }
          smF[300 + wvi*5 + b] = m;
          smF[360 + wvi*5 + b] = ssum;
        }
      }
      __syncthreads();
      if (tid < NBEAM){
        float M = -3.4e38f, Sv = 0.f;
#pragma unroll
        for (int w8 = 0; w8 < 8; ++w8){
          float m2 = smF[300 + w8*5 + tid], s2 = smF[360 + w8*5 + tid];
          if (m2 > M){ Sv = Sv*expf(M - m2) + s2; M = m2; }
          else       { Sv = Sv + s2*expf(m2 - M); }
        }
        astore(pm + wid*5 + tid, M); astore(ps + wid*5 + tid, Sv);
      }
      if (wvi < NBEAM){
        int b = wvi;
        float cval; int cidx;
        if (lane < 40){ cval = smF[((lane/5)*5 + b)*5 + (lane%5)]; cidx = smI[((lane/5)*5 + b)*5 + (lane%5)]; }
        else { cval = -3e38f; cidx = 0x7FFFFFFF; }
        float bv = cval; int bc = cidx;
#pragma unroll
        for (int r = 0; r < 5; ++r){
          float cv2 = bv; int ci2 = bc;
#pragma unroll
          for (int mm = 32; mm; mm >>= 1){
            float ov = __shfl_xor(cv2, mm, 64); int oi = __shfl_xor(ci2, mm, 64);
            bool take = (ov > cv2) || (ov == cv2 && oi < ci2);
            cv2 = take ? ov : cv2; ci2 = take ? oi : ci2;
          }
          if (lane == 0){ astore(pv + (wid*5+b)*5+r, cv2); astore(pidx + (wid*5+b)*5+r, ci2); }
          if (bc == ci2) bv = -3e38f;
        }
      }
    }
    dbar(bi, wid, [&](){
      // ======== Stage D (barrier tail, one WG) ========
      int b5 = wvi;
      if (b5 < NBEAM){
        float m1 = aload(pm + lane*5 + b5), s1 = aload(ps + lane*5 + b5);
        float m2 = aload(pm + (64+lane)*5 + b5), s2 = aload(ps + (64+lane)*5 + b5);
        float M, Sv;
        if (m1 >= m2){ M = m1; Sv = s1 + s2*expf(m2 - m1); }
        else         { M = m2; Sv = s2 + s1*expf(m1 - m2); }
#pragma unroll
        for (int mm = 32; mm; mm >>= 1){
          float om = __shfl_xor(M, mm, 64), os = __shfl_xor(Sv, mm, 64);
          if (om > M){ Sv = Sv*expf(M - om) + os; M = om; }
          else       { Sv = Sv + os*expf(om - M); }
        }
        if (lane == 0){ smF[8 + b5] = M; smF[80 + b5] = logf(Sv); }
        float lv[5]; int li[5];
#pragma unroll
        for (int r = 0; r < 5; ++r){ lv[r] = aload(pv + (lane*5 + b5)*5 + r); li[r] = aload(pidx + (lane*5 + b5)*5 + r); }
        for (int r = 0; r < 5; ++r){
          float nv = aload(pv + ((64+lane)*5 + b5)*5 + r); int ni = aload(pidx + ((64+lane)*5 + b5)*5 + r);
          bool ins = (nv > lv[4]) || (nv == lv[4] && ni < li[4]);
          if (!ins) break;
          lv[4] = nv; li[4] = ni;
#pragma unroll
          for (int p = 4; p > 0; --p){
            bool sw = (lv[p] > lv[p-1]) || (lv[p] == lv[p-1] && li[p] < li[p-1]);
            if (sw){ float tv = lv[p]; lv[p] = lv[p-1]; lv[p-1] = tv;
                     int ti = li[p]; li[p] = li[p-1]; li[p-1] = ti; }
          }
        }
        float cv = lv[0]; int ci = li[0];
#pragma unroll
        for (int r = 0; r < 5; ++r){
          float xv = cv; int xi = ci;
#pragma unroll
          for (int mm = 32; mm; mm >>= 1){
            float ov = __shfl_xor(xv, mm, 64); int oi = __shfl_xor(xi, mm, 64);
            bool take = (ov > xv) || (ov == xv && oi < xi);
            xv = take ? ov : xv; xi = take ? oi : xi;
          }
          if (lane == 0){ smF[16 + b5*5 + r] = xv; smI[16 + b5*5 + r] = xi; }
          if (ci == xi){
            lv[0]=lv[1]; li[0]=li[1]; lv[1]=lv[2]; li[1]=li[2];
            lv[2]=lv[3]; li[2]=li[3]; lv[3]=lv[4]; li[3]=li[4];
            lv[4] = -3e38f; li[4] = 0x7FFFFFFF;
            cv = lv[0]; ci = li[0];
          }
        }
      }
      __syncthreads();
      if (wvi == 0){
        float cval = -3e38f; int cflat = 0x7FFFFFFF;
        int b = lane/5, k = lane - b*5;
        if (lane < 25){
          if (aload(finA + b)){
            if (k == 0){ cval = aload(sc + b) + 0.0f; cflat = b*V_SZ + TOK_EOS; }
          } else {
            cval = ((smF[16 + b*5 + k] - smF[8 + b]) - smF[80 + b]) + aload(sc + b);
            cflat = b*V_SZ + smI[16 + b*5 + k];
          }
        }
        float bv = cval; int bc = cflat;
#pragma unroll
        for (int r = 0; r < 5; ++r){
          float xv = bv; int xi = bc;
#pragma unroll
          for (int mm = 32; mm; mm >>= 1){
            float ov = __shfl_xor(xv, mm, 64); int oi = __shfl_xor(xi, mm, 64);
            bool take = (ov > xv) || (ov == xv && oi < xi);
            xv = take ? ov : xv; xi = take ? oi : xi;
          }
          if (lane == 0){ smF[48 + r] = xv; smI[48 + r] = xi; }
          if (bc == xi) bv = -3e38f;
        }
        if (lane < NBEAM){
          int r = lane;
          float nscore = smF[48 + r]; int nfl = smI[48 + r];
          int par = nfl / V_SZ; int tok = nfl - par*V_SZ;
          int ofin = aload(finA + par); int olen = aload(lenA + par);  // reads before writes (wave-lockstep)
          int nf = (ofin || tok == TOK_EOS) ? 1 : 0;
          int nl = olen + (ofin ? 0 : 1);
          astore(sc + r, nscore); astore(tokA + r, tok); astore(finA + r, nf);
          astore(lenA + r, nl); astore(parA + r, par);
          smI[56 + r] = par; smI[64 + r] = tok; smI[72 + r] = ofin; smI[80 + r] = nl;
          smF[56 + r] = nscore;
        }
      }
      __syncthreads();
      int cur = t & 1, nxt = 1 - cur;
      if (tid < 160){
        int r = tid >> 5, u = tid & 31;
        int par = smI[56 + r];
        int val = aload(seqA + cur*160 + par*32 + u);
        if (u == t) val = smI[72 + r] ? 0 : smI[64 + r];
        astore(seqA + nxt*160 + r*32 + u, val);
      }
      if (t == TMAXX - 1){
        __syncthreads();
        if (tid == 0){
          float nn[5];
#pragma unroll
          for (int r = 0; r < 5; ++r) nn[r] = smF[56 + r] / (float)smI[80 + r];
          int used = 0;
#pragma unroll
          for (int r = 0; r < 5; ++r){
            int best = -1;
            for (int q2 = 0; q2 < 5; ++q2){
              if (used & (1 << q2)) continue;
              if (best < 0 || nn[q2] > nn[best]) best = q2;
            }
            used |= (1 << best);
            smI[88 + r] = best; smF[64 + r] = nn[best];
          }
        }
        __syncthreads();
        if (tid < 160){
          int r = tid >> 5, u = tid & 31;
          int src = smI[88 + r];
          out[tid] = (float)aload(seqA + nxt*160 + src*32 + u);
        }
        if (tid >= 160 && tid < 165) out[tid] = smF[64 + (tid - 160)];
      }
    });
  }
}

extern "C" void kernel_launch(void* const* d_in, const int* in_sizes, int n_in,
                              void* d_out, int out_size, void* d_ws, size_t ws_size,
                              hipStream_t stream)
{
  (void)in_sizes; (void)n_in; (void)out_size; (void)ws_size;
  hipMemsetAsync(d_ws, 0, 8192, stream);   // barrier counters/generations
  float* ws = (float*)d_ws;
  k_gi<<<dim3(256), dim3(256), 0, stream>>>(
      (const int*)d_in[0], (const float*)d_in[1],
      (const float*)d_in[2], (const float*)d_in[4], ws);
  k_enc<<<dim3(GENC), dim3(NT), 0, stream>>>(
      (const float*)d_in[3], (const float*)d_in[5], ws);
  k_ew<<<dim3(128), dim3(NT), 0, stream>>>(
      (const float*)d_in[10], ws);
  k_dec<<<dim3(GW), dim3(NT), 0, stream>>>(
      (const float*)d_in[1],
      (const float*)d_in[6], (const float*)d_in[7],
      (const float*)d_in[8], (const float*)d_in[9],
      (const float*)d_in[10], (const float*)d_in[11],
      (float*)d_out, ws);
}